// Round 1
// baseline (18993.359 us; speedup 1.0000x reference)
//
#include <hip/hip_runtime.h>
#include <math.h>

#define B_   512
#define T_   2048
#define H_   64
#define NS_  32
#define HH_  128   // 2H
#define G4_  256   // 4H
#define EPSF 1e-5f

__device__ __forceinline__ float gelu_f(float x) {
    // exact (erf) GELU, matches jax.nn.gelu(approximate=False)
    return 0.5f * x * (1.0f + erff(x * 0.70710678118654752440f));
}
__device__ __forceinline__ float sigmoid_f(float x) {
    return 1.0f / (1.0f + expf(-x));
}

// ---------------------------------------------------------------------------
// Input projection: seq[b,t,:] = GELU(LN(sensors[b,t,:] @ W1 + b1)) @ W2 + b2
// 1 thread per (b,t) row; weights broadcast from LDS; row kept in registers
// with fully-static indexing (rule #20).
// ---------------------------------------------------------------------------
__global__ void __launch_bounds__(256) inproj_kernel(
    const float* __restrict__ sensors, const float* __restrict__ W1,
    const float* __restrict__ b1, const float* __restrict__ g1,
    const float* __restrict__ bb1, const float* __restrict__ W2,
    const float* __restrict__ b2, float* __restrict__ seq)
{
    __shared__ __align__(16) float W1l[NS_ * H_];   // [k][j]  8 KB
    __shared__ __align__(16) float W2l[H_ * H_];    // [j][j2] 16 KB
    __shared__ float p1[H_], p2[H_], p3[H_], p4[H_];
    const int tid = threadIdx.x;
    {
        const float4* s1 = (const float4*)W1;
        float4* d1 = (float4*)W1l;
        for (int i = tid; i < NS_ * H_ / 4; i += 256) d1[i] = s1[i];
        const float4* s2 = (const float4*)W2;
        float4* d2 = (float4*)W2l;
        for (int i = tid; i < H_ * H_ / 4; i += 256) d2[i] = s2[i];
        if (tid < H_) { p1[tid] = b1[tid]; p2[tid] = g1[tid];
                        p3[tid] = bb1[tid]; p4[tid] = b2[tid]; }
    }
    __syncthreads();

    const long idx = (long)blockIdx.x * 256 + tid;      // < B*T
    const float* srow = sensors + idx * NS_;
    float sv[NS_];
    #pragma unroll
    for (int q = 0; q < NS_ / 4; ++q) {
        float4 v = *(const float4*)&srow[q * 4];
        sv[q*4+0] = v.x; sv[q*4+1] = v.y; sv[q*4+2] = v.z; sv[q*4+3] = v.w;
    }
    float t1[H_];
    #pragma unroll
    for (int jb = 0; jb < H_ / 4; ++jb) {
        float ax = p1[jb*4+0], ay = p1[jb*4+1], az = p1[jb*4+2], aw = p1[jb*4+3];
        #pragma unroll
        for (int k = 0; k < NS_; ++k) {
            float4 w = *(const float4*)&W1l[k * H_ + jb * 4];
            ax += sv[k]*w.x; ay += sv[k]*w.y; az += sv[k]*w.z; aw += sv[k]*w.w;
        }
        t1[jb*4+0] = ax; t1[jb*4+1] = ay; t1[jb*4+2] = az; t1[jb*4+3] = aw;
    }
    // LayerNorm (biased var) + GELU
    float mean = 0.f;
    #pragma unroll
    for (int j = 0; j < H_; ++j) mean += t1[j];
    mean *= (1.0f / H_);
    float var = 0.f;
    #pragma unroll
    for (int j = 0; j < H_; ++j) { float d = t1[j] - mean; var += d * d; }
    var *= (1.0f / H_);
    const float inv = rsqrtf(var + EPSF);
    #pragma unroll
    for (int j = 0; j < H_; ++j) {
        float nv = (t1[j] - mean) * inv * p2[j] + p3[j];
        t1[j] = gelu_f(nv);
    }
    // second linear
    float* orow = seq + idx * H_;
    for (int ob = 0; ob < H_ / 4; ++ob) {               // runtime loop is fine:
        float ax = p4[ob*4+0], ay = p4[ob*4+1];         // t1[] indices stay static
        float az = p4[ob*4+2], aw = p4[ob*4+3];
        #pragma unroll
        for (int j = 0; j < H_; ++j) {
            float4 w = *(const float4*)&W2l[j * H_ + ob * 4];
            ax += t1[j]*w.x; ay += t1[j]*w.y; az += t1[j]*w.z; aw += t1[j]*w.w;
        }
        float4 o; o.x = ax; o.y = ay; o.z = az; o.w = aw;
        *(float4*)&orow[ob * 4] = o;
    }
}

// ---------------------------------------------------------------------------
// One LSTM layer over all T, in-place on seq[B,T,H] (reads h_{l-1}(t), writes
// h_l(t) to the same slot AFTER the step consumed it; next-step input (t+1)
// is prefetched before the current slot is overwritten -> no hazard).
// 256 blocks x 256 threads; block owns batches {2*bid, 2*bid+1}; layer weights
// (128KB) live in LDS for the whole pass. No inter-block communication.
// ---------------------------------------------------------------------------
__global__ void __launch_bounds__(256) lstm_pass_kernel(
    const float* __restrict__ Wg, const float* __restrict__ bg,
    float* __restrict__ seq, int layer)
{
    __shared__ __align__(16) float Wl[HH_ * G4_];   // [k][n] 128 KB
    __shared__ __align__(16) float comb[2][HH_];    // [m][k] = {x_t | h}
    __shared__ __align__(16) float gbuf[2][G4_];
    __shared__ float cst[2][H_];

    const int tid = threadIdx.x;
    const int n = tid;                              // gate column 0..255
    {   // stage layer weights (identity copy, coalesced float4)
        const float4* s4 = (const float4*)(Wg + (size_t)layer * HH_ * G4_);
        float4* d4 = (float4*)Wl;
        for (int i = tid; i < HH_ * G4_ / 4; i += 256) d4[i] = s4[i];
    }
    const float bgn = bg[layer * G4_ + n];

    const int m = tid >> 6;                         // valid for tid<128
    const int d = tid & 63;
    const long rowbase = ((long)(blockIdx.x * 2 + m)) * T_ * H_ + d;

    if (tid < 128) {
        comb[m][d]      = seq[rowbase];             // x(0)
        comb[m][H_ + d] = 0.f;                      // h = 0
        cst[m][d]       = 0.f;                      // c = 0
    }
    __syncthreads();

    for (int t = 0; t < T_; ++t) {
        // prefetch next-step input; latency hides under the matmul
        float xn = 0.f;
        if (tid < 128 && t + 1 < T_) xn = seq[rowbase + (long)(t + 1) * H_];

        float a0a = bgn, a0b = 0.f, a1a = bgn, a1b = 0.f;   // 4 FMA chains
        #pragma unroll
        for (int k4 = 0; k4 < HH_ / 4; ++k4) {
            float4 c0 = *(const float4*)&comb[0][k4 * 4];
            float4 c1 = *(const float4*)&comb[1][k4 * 4];
            float w0 = Wl[(k4 * 4 + 0) * G4_ + n];
            float w1 = Wl[(k4 * 4 + 1) * G4_ + n];
            float w2 = Wl[(k4 * 4 + 2) * G4_ + n];
            float w3 = Wl[(k4 * 4 + 3) * G4_ + n];
            a0a += w0 * c0.x; a0b += w1 * c0.y; a0a += w2 * c0.z; a0b += w3 * c0.w;
            a1a += w0 * c1.x; a1b += w1 * c1.y; a1a += w2 * c1.z; a1b += w3 * c1.w;
        }
        gbuf[0][n] = a0a + a0b;
        gbuf[1][n] = a1a + a1b;
        __syncthreads();

        if (tid < 128) {
            const float ig = sigmoid_f(gbuf[m][d]);
            const float fg = sigmoid_f(gbuf[m][H_ + d]);
            const float gg = tanhf(gbuf[m][2 * H_ + d]);
            const float og = sigmoid_f(gbuf[m][3 * H_ + d]);
            const float cn = fg * cst[m][d] + ig * gg;
            const float hn = og * tanhf(cn);
            cst[m][d] = cn;
            comb[m][H_ + d] = hn;
            comb[m][d] = xn;                        // input for step t+1
            seq[rowbase + (long)t * H_] = hn;       // output of this layer
        }
        __syncthreads();
    }
}

// ---------------------------------------------------------------------------
// Output projection: y = GELU(LN(h3) @ W_out1 + b_out1) @ W_out2 + b_out2
// ---------------------------------------------------------------------------
__global__ void __launch_bounds__(256) outproj_kernel(
    const float* __restrict__ seq, const float* __restrict__ g2,
    const float* __restrict__ b2, const float* __restrict__ W1,
    const float* __restrict__ b1, const float* __restrict__ W2,
    const float* __restrict__ b2o, float* __restrict__ y)
{
    __shared__ __align__(16) float W1l[H_ * H_];    // [j][j2] 16 KB
    __shared__ __align__(16) float W2l[H_ * 4];     // [j2][c] padded to 4
    __shared__ float pg[H_], pb[H_], pb1[H_];
    const int tid = threadIdx.x;
    {
        const float4* s1 = (const float4*)W1;
        float4* d1 = (float4*)W1l;
        for (int i = tid; i < H_ * H_ / 4; i += 256) d1[i] = s1[i];
        if (tid < H_) {
            pg[tid] = g2[tid]; pb[tid] = b2[tid]; pb1[tid] = b1[tid];
            float4 w; w.x = W2[tid*3+0]; w.y = W2[tid*3+1]; w.z = W2[tid*3+2]; w.w = 0.f;
            *(float4*)&W2l[tid * 4] = w;
        }
    }
    __syncthreads();

    const long idx = (long)blockIdx.x * 256 + tid;
    const float* hrow = seq + idx * H_;
    float hv[H_];
    #pragma unroll
    for (int q = 0; q < H_ / 4; ++q) {
        float4 v = *(const float4*)&hrow[q * 4];
        hv[q*4+0] = v.x; hv[q*4+1] = v.y; hv[q*4+2] = v.z; hv[q*4+3] = v.w;
    }
    float mean = 0.f;
    #pragma unroll
    for (int j = 0; j < H_; ++j) mean += hv[j];
    mean *= (1.0f / H_);
    float var = 0.f;
    #pragma unroll
    for (int j = 0; j < H_; ++j) { float dd = hv[j] - mean; var += dd * dd; }
    var *= (1.0f / H_);
    const float inv = rsqrtf(var + EPSF);
    #pragma unroll
    for (int j = 0; j < H_; ++j) hv[j] = (hv[j] - mean) * inv * pg[j] + pb[j];

    float y0 = b2o[0], y1 = b2o[1], y2 = b2o[2];
    for (int ob = 0; ob < H_ / 4; ++ob) {           // runtime loop, hv[] static
        float ax = pb1[ob*4+0], ay = pb1[ob*4+1];
        float az = pb1[ob*4+2], aw = pb1[ob*4+3];
        #pragma unroll
        for (int j = 0; j < H_; ++j) {
            float4 w = *(const float4*)&W1l[j * H_ + ob * 4];
            ax += hv[j]*w.x; ay += hv[j]*w.y; az += hv[j]*w.z; aw += hv[j]*w.w;
        }
        ax = gelu_f(ax); ay = gelu_f(ay); az = gelu_f(az); aw = gelu_f(aw);
        float4 wa = *(const float4*)&W2l[(ob*4+0) * 4];
        float4 wb = *(const float4*)&W2l[(ob*4+1) * 4];
        float4 wc = *(const float4*)&W2l[(ob*4+2) * 4];
        float4 wd = *(const float4*)&W2l[(ob*4+3) * 4];
        y0 += ax*wa.x + ay*wb.x + az*wc.x + aw*wd.x;
        y1 += ax*wa.y + ay*wb.y + az*wc.y + aw*wd.y;
        y2 += ax*wa.z + ay*wb.z + az*wc.z + aw*wd.z;
    }
    y[idx * 3 + 0] = y0;
    y[idx * 3 + 1] = y1;
    y[idx * 3 + 2] = y2;
}

// ---------------------------------------------------------------------------
extern "C" void kernel_launch(void* const* d_in, const int* in_sizes, int n_in,
                              void* d_out, int out_size, void* d_ws, size_t ws_size,
                              hipStream_t stream)
{
    const float* sensors = (const float*)d_in[0];
    const float* W_in1   = (const float*)d_in[1];
    const float* b_in1   = (const float*)d_in[2];
    const float* ln1_g   = (const float*)d_in[3];
    const float* ln1_b   = (const float*)d_in[4];
    const float* W_in2   = (const float*)d_in[5];
    const float* b_in2   = (const float*)d_in[6];
    const float* Wg      = (const float*)d_in[7];
    const float* bg      = (const float*)d_in[8];
    const float* ln2_g   = (const float*)d_in[9];
    const float* ln2_b   = (const float*)d_in[10];
    const float* W_out1  = (const float*)d_in[11];
    const float* b_out1  = (const float*)d_in[12];
    const float* W_out2  = (const float*)d_in[13];
    const float* b_out2  = (const float*)d_in[14];
    float* y   = (float*)d_out;
    float* seq = (float*)d_ws;          // [B,T,H] fp32 = 256 MB, in-place per layer

    inproj_kernel<<<B_ * T_ / 256, 256, 0, stream>>>(
        sensors, W_in1, b_in1, ln1_g, ln1_b, W_in2, b_in2, seq);
    for (int l = 0; l < 4; ++l)
        lstm_pass_kernel<<<B_ / 2, 256, 0, stream>>>(Wg, bg, seq, l);
    outproj_kernel<<<B_ * T_ / 256, 256, 0, stream>>>(
        seq, ln2_g, ln2_b, W_out1, b_out1, W_out2, b_out2, y);
}

// Round 2
// 16429.651 us; speedup vs baseline: 1.1560x; 1.1560x over previous
//
#include <hip/hip_runtime.h>
#include <math.h>

#define B_   512
#define T_   2048
#define H_   64
#define NS_  32
#define HH_  128   // 2H
#define G4_  256   // 4H
#define EPSF 1e-5f

__device__ __forceinline__ float gelu_f(float x) {
    // exact (erf) GELU, matches jax.nn.gelu(approximate=False)
    return 0.5f * x * (1.0f + erff(x * 0.70710678118654752440f));
}
__device__ __forceinline__ float sigmoid_f(float x) {
    return 1.0f / (1.0f + expf(-x));
}

// ---------------------------------------------------------------------------
// Input projection: seq[b,t,:] = GELU(LN(sensors[b,t,:] @ W1 + b1)) @ W2 + b2
// ---------------------------------------------------------------------------
__global__ void __launch_bounds__(256) inproj_kernel(
    const float* __restrict__ sensors, const float* __restrict__ W1,
    const float* __restrict__ b1, const float* __restrict__ g1,
    const float* __restrict__ bb1, const float* __restrict__ W2,
    const float* __restrict__ b2, float* __restrict__ seq)
{
    __shared__ __align__(16) float W1l[NS_ * H_];   // [k][j]  8 KB
    __shared__ __align__(16) float W2l[H_ * H_];    // [j][j2] 16 KB
    __shared__ float p1[H_], p2[H_], p3[H_], p4[H_];
    const int tid = threadIdx.x;
    {
        const float4* s1 = (const float4*)W1;
        float4* d1 = (float4*)W1l;
        for (int i = tid; i < NS_ * H_ / 4; i += 256) d1[i] = s1[i];
        const float4* s2 = (const float4*)W2;
        float4* d2 = (float4*)W2l;
        for (int i = tid; i < H_ * H_ / 4; i += 256) d2[i] = s2[i];
        if (tid < H_) { p1[tid] = b1[tid]; p2[tid] = g1[tid];
                        p3[tid] = bb1[tid]; p4[tid] = b2[tid]; }
    }
    __syncthreads();

    const long idx = (long)blockIdx.x * 256 + tid;      // < B*T
    const float* srow = sensors + idx * NS_;
    float sv[NS_];
    #pragma unroll
    for (int q = 0; q < NS_ / 4; ++q) {
        float4 v = *(const float4*)&srow[q * 4];
        sv[q*4+0] = v.x; sv[q*4+1] = v.y; sv[q*4+2] = v.z; sv[q*4+3] = v.w;
    }
    float t1[H_];
    #pragma unroll
    for (int jb = 0; jb < H_ / 4; ++jb) {
        float ax = p1[jb*4+0], ay = p1[jb*4+1], az = p1[jb*4+2], aw = p1[jb*4+3];
        #pragma unroll
        for (int k = 0; k < NS_; ++k) {
            float4 w = *(const float4*)&W1l[k * H_ + jb * 4];
            ax += sv[k]*w.x; ay += sv[k]*w.y; az += sv[k]*w.z; aw += sv[k]*w.w;
        }
        t1[jb*4+0] = ax; t1[jb*4+1] = ay; t1[jb*4+2] = az; t1[jb*4+3] = aw;
    }
    float mean = 0.f;
    #pragma unroll
    for (int j = 0; j < H_; ++j) mean += t1[j];
    mean *= (1.0f / H_);
    float var = 0.f;
    #pragma unroll
    for (int j = 0; j < H_; ++j) { float d = t1[j] - mean; var += d * d; }
    var *= (1.0f / H_);
    const float inv = rsqrtf(var + EPSF);
    #pragma unroll
    for (int j = 0; j < H_; ++j) {
        float nv = (t1[j] - mean) * inv * p2[j] + p3[j];
        t1[j] = gelu_f(nv);
    }
    float* orow = seq + idx * H_;
    for (int ob = 0; ob < H_ / 4; ++ob) {
        float ax = p4[ob*4+0], ay = p4[ob*4+1];
        float az = p4[ob*4+2], aw = p4[ob*4+3];
        #pragma unroll
        for (int j = 0; j < H_; ++j) {
            float4 w = *(const float4*)&W2l[j * H_ + ob * 4];
            ax += t1[j]*w.x; ay += t1[j]*w.y; az += t1[j]*w.z; aw += t1[j]*w.w;
        }
        float4 o; o.x = ax; o.y = ay; o.z = az; o.w = aw;
        *(float4*)&orow[ob * 4] = o;
    }
}

// ---------------------------------------------------------------------------
// One LSTM layer over all T. Weight-stationary in VGPRs:
//   256 threads = 4 waves; waves {0,1} -> batch row 0, waves {2,3} -> row 1.
//   Lane owns gate columns {nb+2l, nb+2l+1} (nb = 0 or 128) for all 128 k:
//   256 VGPRs of weights, loaded once. Per step, LDS serves only the
//   broadcast of comb=[x|h] (32 uniform-address ds_read_b128 per wave) and
//   the 256-gate exchange. Waves 0,2 ("writers") run the nonlinearity, keep
//   the c state in registers, and update comb/seq.
// ---------------------------------------------------------------------------
__global__ void __launch_bounds__(256, 1) lstm_pass_kernel(
    const float* __restrict__ Wg, const float* __restrict__ bg,
    float* __restrict__ seq, int layer)
{
    __shared__ __align__(16) float combL[2][HH_];   // [row][x|h]  1 KB
    __shared__ __align__(16) float gbuf[2][G4_];    // [row][gate] 2 KB

    const int tid = threadIdx.x;
    const int w   = tid >> 6;              // wave 0..3
    const int l   = tid & 63;
    const int m   = w >> 1;                // batch row within block
    const int nb  = (w & 1) * 128;         // gate-column base
    const int n0  = nb + 2 * l;            // this lane's two gate columns
    const bool writer = (w & 1) == 0;      // waves 0,2

    // ---- load weight columns into registers (once) ----
    const float* Wl = Wg + (size_t)layer * HH_ * G4_;
    float2 wv[HH_];
    #pragma unroll
    for (int k = 0; k < HH_; ++k)
        wv[k] = *(const float2*)&Wl[k * G4_ + n0];
    const float2 bg2 = *(const float2*)&bg[layer * G4_ + n0];

    const long rowbase = ((long)(blockIdx.x * 2 + m)) * T_ * H_ + l;

    float c_reg = 0.f;
    if (writer) {
        combL[m][l]      = seq[rowbase];    // x(0) = previous layer h(0)
        combL[m][H_ + l] = 0.f;             // h(-1) = 0
    }
    __syncthreads();

    for (int t = 0; t < T_; ++t) {
        // prefetch next input; global latency hides under the 256-FMA matmul
        float xn = 0.f;
        if (writer && t + 1 < T_) xn = seq[rowbase + (long)(t + 1) * H_];

        // gates[n0], gates[n0+1] = bias + comb . W[:,n0..n0+1]
        float a0 = bg2.x, a1 = bg2.y, b0 = 0.f, b1 = 0.f;  // 4 FMA chains
        #pragma unroll
        for (int k4 = 0; k4 < HH_ / 4; ++k4) {
            float4 cb = *(const float4*)&combL[m][k4 * 4];  // wave-uniform: broadcast
            a0 += cb.x * wv[k4*4+0].x;  a1 += cb.x * wv[k4*4+0].y;
            b0 += cb.y * wv[k4*4+1].x;  b1 += cb.y * wv[k4*4+1].y;
            a0 += cb.z * wv[k4*4+2].x;  a1 += cb.z * wv[k4*4+2].y;
            b0 += cb.w * wv[k4*4+3].x;  b1 += cb.w * wv[k4*4+3].y;
        }
        float2 g2; g2.x = a0 + b0; g2.y = a1 + b1;
        *(float2*)&gbuf[m][n0] = g2;
        __syncthreads();

        if (writer) {
            const float ig = sigmoid_f(gbuf[m][l]);
            const float fg = sigmoid_f(gbuf[m][H_ + l]);
            const float gg = tanhf(gbuf[m][2 * H_ + l]);
            const float og = sigmoid_f(gbuf[m][3 * H_ + l]);
            c_reg = fg * c_reg + ig * gg;
            const float hn = og * tanhf(c_reg);
            combL[m][H_ + l] = hn;          // h for step t+1
            combL[m][l]      = xn;          // x for step t+1
            seq[rowbase + (long)t * H_] = hn;   // this layer's output
        }
        __syncthreads();
    }
}

// ---------------------------------------------------------------------------
// Output projection: y = GELU(LN(h3) @ W_out1 + b_out1) @ W_out2 + b_out2
// ---------------------------------------------------------------------------
__global__ void __launch_bounds__(256) outproj_kernel(
    const float* __restrict__ seq, const float* __restrict__ g2,
    const float* __restrict__ b2, const float* __restrict__ W1,
    const float* __restrict__ b1, const float* __restrict__ W2,
    const float* __restrict__ b2o, float* __restrict__ y)
{
    __shared__ __align__(16) float W1l[H_ * H_];    // [j][j2] 16 KB
    __shared__ __align__(16) float W2l[H_ * 4];     // [j2][c] padded to 4
    __shared__ float pg[H_], pb[H_], pb1[H_];
    const int tid = threadIdx.x;
    {
        const float4* s1 = (const float4*)W1;
        float4* d1 = (float4*)W1l;
        for (int i = tid; i < H_ * H_ / 4; i += 256) d1[i] = s1[i];
        if (tid < H_) {
            pg[tid] = g2[tid]; pb[tid] = b2[tid]; pb1[tid] = b1[tid];
            float4 w; w.x = W2[tid*3+0]; w.y = W2[tid*3+1]; w.z = W2[tid*3+2]; w.w = 0.f;
            *(float4*)&W2l[tid * 4] = w;
        }
    }
    __syncthreads();

    const long idx = (long)blockIdx.x * 256 + tid;
    const float* hrow = seq + idx * H_;
    float hv[H_];
    #pragma unroll
    for (int q = 0; q < H_ / 4; ++q) {
        float4 v = *(const float4*)&hrow[q * 4];
        hv[q*4+0] = v.x; hv[q*4+1] = v.y; hv[q*4+2] = v.z; hv[q*4+3] = v.w;
    }
    float mean = 0.f;
    #pragma unroll
    for (int j = 0; j < H_; ++j) mean += hv[j];
    mean *= (1.0f / H_);
    float var = 0.f;
    #pragma unroll
    for (int j = 0; j < H_; ++j) { float dd = hv[j] - mean; var += dd * dd; }
    var *= (1.0f / H_);
    const float inv = rsqrtf(var + EPSF);
    #pragma unroll
    for (int j = 0; j < H_; ++j) hv[j] = (hv[j] - mean) * inv * pg[j] + pb[j];

    float y0 = b2o[0], y1 = b2o[1], y2 = b2o[2];
    for (int ob = 0; ob < H_ / 4; ++ob) {
        float ax = pb1[ob*4+0], ay = pb1[ob*4+1];
        float az = pb1[ob*4+2], aw = pb1[ob*4+3];
        #pragma unroll
        for (int j = 0; j < H_; ++j) {
            float4 w = *(const float4*)&W1l[j * H_ + ob * 4];
            ax += hv[j]*w.x; ay += hv[j]*w.y; az += hv[j]*w.z; aw += hv[j]*w.w;
        }
        ax = gelu_f(ax); ay = gelu_f(ay); az = gelu_f(az); aw = gelu_f(aw);
        float4 wa = *(const float4*)&W2l[(ob*4+0) * 4];
        float4 wb = *(const float4*)&W2l[(ob*4+1) * 4];
        float4 wc = *(const float4*)&W2l[(ob*4+2) * 4];
        float4 wd = *(const float4*)&W2l[(ob*4+3) * 4];
        y0 += ax*wa.x + ay*wb.x + az*wc.x + aw*wd.x;
        y1 += ax*wa.y + ay*wb.y + az*wc.y + aw*wd.y;
        y2 += ax*wa.z + ay*wb.z + az*wc.z + aw*wd.z;
    }
    y[idx * 3 + 0] = y0;
    y[idx * 3 + 1] = y1;
    y[idx * 3 + 2] = y2;
}

// ---------------------------------------------------------------------------
extern "C" void kernel_launch(void* const* d_in, const int* in_sizes, int n_in,
                              void* d_out, int out_size, void* d_ws, size_t ws_size,
                              hipStream_t stream)
{
    const float* sensors = (const float*)d_in[0];
    const float* W_in1   = (const float*)d_in[1];
    const float* b_in1   = (const float*)d_in[2];
    const float* ln1_g   = (const float*)d_in[3];
    const float* ln1_b   = (const float*)d_in[4];
    const float* W_in2   = (const float*)d_in[5];
    const float* b_in2   = (const float*)d_in[6];
    const float* Wg      = (const float*)d_in[7];
    const float* bg      = (const float*)d_in[8];
    const float* ln2_g   = (const float*)d_in[9];
    const float* ln2_b   = (const float*)d_in[10];
    const float* W_out1  = (const float*)d_in[11];
    const float* b_out1  = (const float*)d_in[12];
    const float* W_out2  = (const float*)d_in[13];
    const float* b_out2  = (const float*)d_in[14];
    float* y   = (float*)d_out;
    float* seq = (float*)d_ws;          // [B,T,H] fp32 = 256 MB, in-place per layer

    inproj_kernel<<<B_ * T_ / 256, 256, 0, stream>>>(
        sensors, W_in1, b_in1, ln1_g, ln1_b, W_in2, b_in2, seq);
    for (int l = 0; l < 4; ++l)
        lstm_pass_kernel<<<B_ / 2, 256, 0, stream>>>(Wg, bg, seq, l);
    outproj_kernel<<<B_ * T_ / 256, 256, 0, stream>>>(
        seq, ln2_g, ln2_b, W_out1, b_out1, W_out2, b_out2, y);
}

// Round 3
// 4134.371 us; speedup vs baseline: 4.5940x; 3.9739x over previous
//
#include <hip/hip_runtime.h>
#include <math.h>

#define B_   512
#define T_   2048
#define H_   64
#define NS_  32
#define HH_  128   // 2H
#define G4_  256   // 4H
#define EPSF 1e-5f

typedef _Float16 h2 __attribute__((ext_vector_type(2)));
typedef _Float16 h4 __attribute__((ext_vector_type(4)));
typedef _Float16 h8 __attribute__((ext_vector_type(8)));
union H8u { h8 v; h2 p[4]; };

#if __has_builtin(__builtin_amdgcn_fdot2)
__device__ __forceinline__ float fdot2(h2 a, h2 b, float c) {
    return __builtin_amdgcn_fdot2(a, b, c, false);   // v_dot2_f32_f16
}
#else
__device__ __forceinline__ float fdot2(h2 a, h2 b, float c) {
    return c + (float)a[0] * (float)b[0] + (float)a[1] * (float)b[1];
}
#endif

__device__ __forceinline__ float gelu_f(float x) {
    return 0.5f * x * (1.0f + erff(x * 0.70710678118654752440f));
}
__device__ __forceinline__ float sigmoid_f(float x) {
    return 1.0f / (1.0f + __expf(-x));
}
__device__ __forceinline__ float tanh_f(float x) {
    return 1.0f - 2.0f / (__expf(2.0f * x) + 1.0f);  // exact at +-inf, ~1e-7 rel err
}

// ---------------------------------------------------------------------------
// Input projection -> packed fp16 x-sequence  seqh[B][T][64]
// ---------------------------------------------------------------------------
__global__ void __launch_bounds__(256) inproj_kernel(
    const float* __restrict__ sensors, const float* __restrict__ W1,
    const float* __restrict__ b1, const float* __restrict__ g1,
    const float* __restrict__ bb1, const float* __restrict__ W2,
    const float* __restrict__ b2, _Float16* __restrict__ seqh)
{
    __shared__ __align__(16) float W1l[NS_ * H_];
    __shared__ __align__(16) float W2l[H_ * H_];
    __shared__ float p1[H_], p2[H_], p3[H_], p4[H_];
    const int tid = threadIdx.x;
    {
        const float4* s1 = (const float4*)W1;
        float4* d1 = (float4*)W1l;
        for (int i = tid; i < NS_ * H_ / 4; i += 256) d1[i] = s1[i];
        const float4* s2 = (const float4*)W2;
        float4* d2 = (float4*)W2l;
        for (int i = tid; i < H_ * H_ / 4; i += 256) d2[i] = s2[i];
        if (tid < H_) { p1[tid] = b1[tid]; p2[tid] = g1[tid];
                        p3[tid] = bb1[tid]; p4[tid] = b2[tid]; }
    }
    __syncthreads();

    const long idx = (long)blockIdx.x * 256 + tid;
    const float* srow = sensors + idx * NS_;
    float sv[NS_];
    #pragma unroll
    for (int q = 0; q < NS_ / 4; ++q) {
        float4 v = *(const float4*)&srow[q * 4];
        sv[q*4+0] = v.x; sv[q*4+1] = v.y; sv[q*4+2] = v.z; sv[q*4+3] = v.w;
    }
    float t1[H_];
    #pragma unroll
    for (int jb = 0; jb < H_ / 4; ++jb) {
        float ax = p1[jb*4+0], ay = p1[jb*4+1], az = p1[jb*4+2], aw = p1[jb*4+3];
        #pragma unroll
        for (int k = 0; k < NS_; ++k) {
            float4 w = *(const float4*)&W1l[k * H_ + jb * 4];
            ax += sv[k]*w.x; ay += sv[k]*w.y; az += sv[k]*w.z; aw += sv[k]*w.w;
        }
        t1[jb*4+0] = ax; t1[jb*4+1] = ay; t1[jb*4+2] = az; t1[jb*4+3] = aw;
    }
    float mean = 0.f;
    #pragma unroll
    for (int j = 0; j < H_; ++j) mean += t1[j];
    mean *= (1.0f / H_);
    float var = 0.f;
    #pragma unroll
    for (int j = 0; j < H_; ++j) { float d = t1[j] - mean; var += d * d; }
    var *= (1.0f / H_);
    const float inv = rsqrtf(var + EPSF);
    #pragma unroll
    for (int j = 0; j < H_; ++j) {
        float nv = (t1[j] - mean) * inv * p2[j] + p3[j];
        t1[j] = gelu_f(nv);
    }
    _Float16* orow = seqh + idx * H_;
    for (int ob = 0; ob < H_ / 4; ++ob) {
        float ax = p4[ob*4+0], ay = p4[ob*4+1];
        float az = p4[ob*4+2], aw = p4[ob*4+3];
        #pragma unroll
        for (int j = 0; j < H_; ++j) {
            float4 w = *(const float4*)&W2l[j * H_ + ob * 4];
            ax += t1[j]*w.x; ay += t1[j]*w.y; az += t1[j]*w.z; aw += t1[j]*w.w;
        }
        h4 o; o[0] = (_Float16)ax; o[1] = (_Float16)ay;
              o[2] = (_Float16)az; o[3] = (_Float16)aw;
        *(h4*)&orow[ob * 4] = o;
    }
}

// ---------------------------------------------------------------------------
// Fused 4-layer pipelined LSTM over all T in ONE kernel.
//   Block = 512 thr = 8 waves; wave (l = w>>1, half = w&1).
//   Matmul duty: wave (l,half) owns gate cols [half*128, half*128+128),
//     lane -> col pair n0 = half*128+2*lane, for BOTH batch rows; weights
//     fp16-packed along k in 128 VGPRs (v_dot2_f32_f16, fp32 accum).
//   Nonlin duty: wave (l,half) -> (layer l, row half), lane = hidden unit.
//   Pipeline: at step s layer l processes t = s-l; h hands off via LDS.
// ---------------------------------------------------------------------------
__global__ void __launch_bounds__(512, 2) lstm_fused_kernel(
    const float* __restrict__ Wg, const float* __restrict__ bg,
    const _Float16* __restrict__ xin,   // [B][T][64] fp16 (inproj output)
    _Float16* __restrict__ h3f16,       // in-place h3 output (if h3f32 null)
    float* __restrict__ h3f32)          // optional fp32 h3 output
{
    __shared__ h8 comb[4][2][16];          // [layer][row][k/8]; k<64 = x, k>=64 = h
    __shared__ float gbuf[4][2][G4_];      // 8 KB

    const int tid  = threadIdx.x;
    const int wv_  = tid >> 6;
    const int lane = tid & 63;
    const int l    = wv_ >> 1;
    const int half = wv_ & 1;
    const int n0   = half * 128 + 2 * lane;

    // ---- fp16-pack weight columns into registers (once) ----
    const float* W = Wg + (size_t)l * HH_ * G4_;
    h2 w0[64], w1[64];
    #pragma unroll
    for (int kk = 0; kk < 64; ++kk) {
        float2 wa = *(const float2*)&W[(2 * kk)     * G4_ + n0];
        float2 wb = *(const float2*)&W[(2 * kk + 1) * G4_ + n0];
        h2 a, b;
        a[0] = (_Float16)wa.x; a[1] = (_Float16)wb.x;
        b[0] = (_Float16)wa.y; b[1] = (_Float16)wb.y;
        w0[kk] = a; w1[kk] = b;
    }
    const float bgx = bg[l * G4_ + n0];
    const float bgy = bg[l * G4_ + n0 + 1];

    const int  grow    = blockIdx.x * 2 + half;     // row for nonlin duty
    const long rowbase = (long)grow * T_ * H_;

    _Float16* combh = (_Float16*)comb;
    const int cidx = (l * 2 + half) * 128;          // halfword base of comb[l][half]

    float c_reg = 0.f;
    combh[cidx + 64 + lane] = (_Float16)0.f;        // h_l(-1) = 0
    if (l == 0) combh[cidx + lane] = xin[rowbase + lane];   // x_0(0)
    __syncthreads();

    for (int s = 0; s < T_ + 3; ++s) {
        const bool act = (s >= l) && (s - l < T_);
        _Float16 xnext = (_Float16)0.f;
        if (act) {
            if (l == 0 && s + 1 < T_)               // prefetch next x under matmul
                xnext = xin[rowbase + (long)(s + 1) * H_ + lane];
            float a00 = bgx, a01 = bgy, a10 = bgx, a11 = bgy;  // 4 indep chains
            #pragma unroll
            for (int i = 0; i < 16; ++i) {
                H8u u0, u1;
                u0.v = comb[l][0][i];               // wave-uniform broadcast b128
                u1.v = comb[l][1][i];
                #pragma unroll
                for (int j = 0; j < 4; ++j) {
                    const int kk = i * 4 + j;
                    a00 = fdot2(u0.p[j], w0[kk], a00);
                    a01 = fdot2(u0.p[j], w1[kk], a01);
                    a10 = fdot2(u1.p[j], w0[kk], a10);
                    a11 = fdot2(u1.p[j], w1[kk], a11);
                }
            }
            float2 r0; r0.x = a00; r0.y = a01;
            float2 r1; r1.x = a10; r1.y = a11;
            *(float2*)&gbuf[l][0][n0] = r0;
            *(float2*)&gbuf[l][1][n0] = r1;
        }
        __syncthreads();
        if (act) {
            const int t = s - l;
            const float gi = gbuf[l][half][lane];
            const float gf = gbuf[l][half][64  + lane];
            const float gg = gbuf[l][half][128 + lane];
            const float go = gbuf[l][half][192 + lane];
            const float ig = sigmoid_f(gi);
            const float fg = sigmoid_f(gf);
            const float g_ = tanh_f(gg);
            const float og = sigmoid_f(go);
            c_reg = fg * c_reg + ig * g_;
            const float hn = og * tanh_f(c_reg);
            const _Float16 hh = (_Float16)hn;
            combh[cidx + 64 + lane] = hh;                       // h_l(t)
            if (l < 3) combh[((l + 1) * 2 + half) * 128 + lane] = hh;  // x_{l+1}(t)
            else if (h3f32) h3f32[rowbase + (long)t * H_ + lane] = hn;
            else            h3f16[rowbase + (long)t * H_ + lane] = hh;
            if (l == 0 && s + 1 < T_) combh[cidx + lane] = xnext;      // x_0(t+1)
        }
        __syncthreads();
    }
}

// ---------------------------------------------------------------------------
// Output projection: y = GELU(LN(h3) @ W_out1 + b_out1) @ W_out2 + b_out2
// ---------------------------------------------------------------------------
__global__ void __launch_bounds__(256) outproj_kernel(
    const _Float16* __restrict__ h16, const float* __restrict__ h32, int use32,
    const float* __restrict__ g2, const float* __restrict__ b2,
    const float* __restrict__ W1, const float* __restrict__ b1,
    const float* __restrict__ W2, const float* __restrict__ b2o,
    float* __restrict__ y)
{
    __shared__ __align__(16) float W1l[H_ * H_];
    __shared__ __align__(16) float W2l[H_ * 4];
    __shared__ float pg[H_], pb[H_], pb1[H_];
    const int tid = threadIdx.x;
    {
        const float4* s1 = (const float4*)W1;
        float4* d1 = (float4*)W1l;
        for (int i = tid; i < H_ * H_ / 4; i += 256) d1[i] = s1[i];
        if (tid < H_) {
            pg[tid] = g2[tid]; pb[tid] = b2[tid]; pb1[tid] = b1[tid];
            float4 w; w.x = W2[tid*3+0]; w.y = W2[tid*3+1]; w.z = W2[tid*3+2]; w.w = 0.f;
            *(float4*)&W2l[tid * 4] = w;
        }
    }
    __syncthreads();

    const long idx = (long)blockIdx.x * 256 + tid;
    float hv[H_];
    if (use32) {
        const float* hrow = h32 + idx * H_;
        #pragma unroll
        for (int q = 0; q < H_ / 4; ++q) {
            float4 v = *(const float4*)&hrow[q * 4];
            hv[q*4+0] = v.x; hv[q*4+1] = v.y; hv[q*4+2] = v.z; hv[q*4+3] = v.w;
        }
    } else {
        const _Float16* hrow = h16 + idx * H_;
        #pragma unroll
        for (int q = 0; q < H_ / 8; ++q) {
            h8 v = *(const h8*)&hrow[q * 8];
            #pragma unroll
            for (int j = 0; j < 8; ++j) hv[q*8+j] = (float)v[j];
        }
    }
    float mean = 0.f;
    #pragma unroll
    for (int j = 0; j < H_; ++j) mean += hv[j];
    mean *= (1.0f / H_);
    float var = 0.f;
    #pragma unroll
    for (int j = 0; j < H_; ++j) { float dd = hv[j] - mean; var += dd * dd; }
    var *= (1.0f / H_);
    const float inv = rsqrtf(var + EPSF);
    #pragma unroll
    for (int j = 0; j < H_; ++j) hv[j] = (hv[j] - mean) * inv * pg[j] + pb[j];

    float y0 = b2o[0], y1 = b2o[1], y2 = b2o[2];
    for (int ob = 0; ob < H_ / 4; ++ob) {
        float ax = pb1[ob*4+0], ay = pb1[ob*4+1];
        float az = pb1[ob*4+2], aw = pb1[ob*4+3];
        #pragma unroll
        for (int j = 0; j < H_; ++j) {
            float4 w = *(const float4*)&W1l[j * H_ + ob * 4];
            ax += hv[j]*w.x; ay += hv[j]*w.y; az += hv[j]*w.z; aw += hv[j]*w.w;
        }
        ax = gelu_f(ax); ay = gelu_f(ay); az = gelu_f(az); aw = gelu_f(aw);
        float4 wa = *(const float4*)&W2l[(ob*4+0) * 4];
        float4 wb = *(const float4*)&W2l[(ob*4+1) * 4];
        float4 wc = *(const float4*)&W2l[(ob*4+2) * 4];
        float4 wd = *(const float4*)&W2l[(ob*4+3) * 4];
        y0 += ax*wa.x + ay*wb.x + az*wc.x + aw*wd.x;
        y1 += ax*wa.y + ay*wb.y + az*wc.y + aw*wd.y;
        y2 += ax*wa.z + ay*wb.z + az*wc.z + aw*wd.z;
    }
    y[idx * 3 + 0] = y0;
    y[idx * 3 + 1] = y1;
    y[idx * 3 + 2] = y2;
}

// ---------------------------------------------------------------------------
extern "C" void kernel_launch(void* const* d_in, const int* in_sizes, int n_in,
                              void* d_out, int out_size, void* d_ws, size_t ws_size,
                              hipStream_t stream)
{
    const float* sensors = (const float*)d_in[0];
    const float* W_in1   = (const float*)d_in[1];
    const float* b_in1   = (const float*)d_in[2];
    const float* ln1_g   = (const float*)d_in[3];
    const float* ln1_b   = (const float*)d_in[4];
    const float* W_in2   = (const float*)d_in[5];
    const float* b_in2   = (const float*)d_in[6];
    const float* Wg      = (const float*)d_in[7];
    const float* bg      = (const float*)d_in[8];
    const float* ln2_g   = (const float*)d_in[9];
    const float* ln2_b   = (const float*)d_in[10];
    const float* W_out1  = (const float*)d_in[11];
    const float* b_out1  = (const float*)d_in[12];
    const float* W_out2  = (const float*)d_in[13];
    const float* b_out2  = (const float*)d_in[14];
    float* y = (float*)d_out;

    const size_t elems = (size_t)B_ * T_ * H_;
    _Float16* seqh = (_Float16*)d_ws;               // 128 MB fp16 x/h buffer
    float* h3f32 = nullptr;
    int use32 = 0;
    if (ws_size >= elems * 2 + elems * 4) {         // room for fp32 h3 too
        h3f32 = (float*)((char*)d_ws + elems * 2);
        use32 = 1;
    }

    inproj_kernel<<<B_ * T_ / 256, 256, 0, stream>>>(
        sensors, W_in1, b_in1, ln1_g, ln1_b, W_in2, b_in2, seqh);
    lstm_fused_kernel<<<B_ / 2, 512, 0, stream>>>(Wg, bg, seqh, seqh, h3f32);
    outproj_kernel<<<B_ * T_ / 256, 256, 0, stream>>>(
        seqh, h3f32, use32, ln2_g, ln2_b, W_out1, b_out1, W_out2, b_out2, y);
}